// Round 12
// baseline (135.910 us; speedup 1.0000x reference)
//
#include <hip/hip_runtime.h>

#define TT 3
#define CCH 32
#define HH 256
#define WW 256
#define KK 7
#define NQ 64
#define QPB 8             // queries per block -> 1536 blocks = 6/CU
#define V1W 48            // y tile row stride == DMA load width (cols w0..w0+47)
#define V1R 14
#define V1N (V1R*V1W)     // 672 dwords per channel plane (mod 32 == 0)
#define V0W 40            // x tile row stride == load width (cols w0x..w0x+39)
#define V0R 7
#define V0N (V0R*V0W)     // 280 dwords per channel plane
#define CHC 8             // channels per chunk
#define NCHUNK 4

__device__ __forceinline__ int refl(int i, int n) {
    i = i < 0 ? -i : i;
    return i >= n ? 2*(n-1) - i : i;
}

__device__ __forceinline__ void gload_lds(const float* g, float* l) {
    __builtin_amdgcn_global_load_lds(
        (const __attribute__((address_space(1))) unsigned int*)g,
        (__attribute__((address_space(3))) unsigned int*)l, 4, 0, 0);
}

// load x row PI (2x ds_read_b128) into named regs
#define XLD(PI, XA, XB) { const float4* xp = (const float4*)(xb + (PI)*V0W); \
                          XA = xp[0]; XB = xp[1]; }
// load y row RR (4x ds_read_b128) into named regs
#define YLD(RR, N0,N1,N2,N3) { const float4* yp = (const float4*)(yb + (RR)*V1W); \
                               N0 = yp[0]; N1 = yp[1]; N2 = yp[2]; N3 = yp[3]; }
#define YMAT(C0,C1,C2,C3) const float y[16] = { \
    C0.x,C0.y,C0.z,C0.w, C1.x,C1.y,C1.z,C1.w, \
    C2.x,C2.y,C2.z,C2.w, C3.x,C3.y,C3.z,C3.w };
// 56-FMA block: acc row L += patch row (XA,XB) against y window
#define FROW(L, XA, XB) { _Pragma("unroll") for (int sw = 0; sw < 8; ++sw) { \
    acc[L][sw] += XA.x*y[sw+0]; acc[L][sw] += XA.y*y[sw+1]; \
    acc[L][sw] += XA.z*y[sw+2]; acc[L][sw] += XA.w*y[sw+3]; \
    acc[L][sw] += XB.x*y[sw+4]; acc[L][sw] += XB.y*y[sw+5]; \
    acc[L][sw] += XB.z*y[sw+6]; } }

// NOTE: no min-waves launch bound — (256,>=4) provokes VGPR under-allocation
// + scratch spill (R4/R9: WRITE_SIZE 97-193 MB). Let the allocator run free.
__global__ __launch_bounds__(256)
void nls_kernel(const float* __restrict__ vid0, const float* __restrict__ vid1,
                float* __restrict__ out) {
    __shared__ float v1s[CHC * V1N];   // 21504 B
    __shared__ float v0s[CHC * V0N];   //  8960 B -> 30464 total, 5 blocks/CU cap

    const int bx  = blockIdx.x;
    const int t   = bx >> 9;             // 512 blocks per frame
    const int rem = bx & 511;
    const int qy  = rem >> 3;
    const int q0  = (rem & 7) * QPB;
    const int qh  = qy * 4;
    const int w0  = 4*q0 - 7;            // v1 tile col origin
    const int w0x = 4*q0 - 3;            // v0 tile col origin

    const int tid   = threadIdx.x;
    const int qwi   = tid & 7;           // bits 0-2: query
    const int clane = (tid >> 3) & 7;    // bits 3-5: channel within chunk
    const int shq   = tid >> 6;          // wave id: sh pair {2shq-4, 2shq-3}

    // staging offsets (channel-independent, pre-reflected)
    int off1[3];
#pragma unroll
    for (int k = 0; k < 3; ++k) {
        int idx = tid + 256*k;
        if (idx < V1N) {
            int r = idx / V1W, wi = idx - r*V1W;
            off1[k] = refl(qh + r - 7, HH) * WW + refl(w0 + wi, WW);
        } else off1[k] = 0;
    }
    int off0[2];
#pragma unroll
    for (int k = 0; k < 2; ++k) {
        int idx = tid + 256*k;
        if (idx < V0N) {
            int r = idx / V0W, wi = idx - r*V0W;
            off0[k] = refl(qh + r - 3, HH) * WW + refl(w0x + wi, WW);
        } else off0[k] = 0;
    }

    float acc[2][8];
#pragma unroll
    for (int l = 0; l < 2; ++l)
#pragma unroll
        for (int b = 0; b < 8; ++b) acc[l][b] = 0.f;

    const float* g0t = vid0 + (size_t)t * (CCH*HH*WW);
    const float* g1t = vid1 + (size_t)t * (CCH*HH*WW);

#pragma unroll 1
    for (int s = 0; s < NCHUNK; ++s) {
        __syncthreads();   // previous chunk's LDS reads complete before overwrite
        // ---- async DMA: v1 + v0 chunk straight into LDS ----
#pragma unroll
        for (int ch = 0; ch < CHC; ++ch) {
            const float* p1 = g1t + (size_t)(CHC*s + ch) * (HH*WW);
            float* lb = &v1s[ch*V1N + (tid & ~63)];
            gload_lds(p1 + off1[0], lb);
            gload_lds(p1 + off1[1], lb + 256);
            if (tid < V1N - 512)
                gload_lds(p1 + off1[2], lb + 512);
        }
#pragma unroll
        for (int ch = 0; ch < CHC; ++ch) {
            const float* p0 = g0t + (size_t)(CHC*s + ch) * (HH*WW);
            float* lb0 = &v0s[ch*V0N + (tid & ~63)];
            gload_lds(p0 + off0[0], lb0);
            if (tid < V0N - 256)
                gload_lds(p0 + off0[1], lb0 + 256);
        }
        __syncthreads();   // DMA drained

        // ---- compute: y rows 2shq+rr (rr 0..7); acc[l] pairs x row rr-l ----
        const float* xb = &v0s[clane*V0N + 4*qwi];
        const float* yb = &v1s[clane*V1N + 2*shq*V1W + 4*qwi];
        float4 Xa0,Xa1, Xb0,Xb1, Xc0,Xc1;
        float4 Ya0,Ya1,Ya2,Ya3, Yb0,Yb1,Yb2,Yb3;
        XLD(0, Xa0,Xa1)
        YLD(0, Ya0,Ya1,Ya2,Ya3)
        { YLD(1, Yb0,Yb1,Yb2,Yb3) XLD(1, Xb0,Xb1) YMAT(Ya0,Ya1,Ya2,Ya3)
          FROW(0, Xa0,Xa1) }
        { YLD(2, Ya0,Ya1,Ya2,Ya3) XLD(2, Xc0,Xc1) YMAT(Yb0,Yb1,Yb2,Yb3)
          FROW(0, Xb0,Xb1) FROW(1, Xa0,Xa1) }
        { YLD(3, Yb0,Yb1,Yb2,Yb3) XLD(3, Xa0,Xa1) YMAT(Ya0,Ya1,Ya2,Ya3)
          FROW(0, Xc0,Xc1) FROW(1, Xb0,Xb1) }
        { YLD(4, Ya0,Ya1,Ya2,Ya3) XLD(4, Xb0,Xb1) YMAT(Yb0,Yb1,Yb2,Yb3)
          FROW(0, Xa0,Xa1) FROW(1, Xc0,Xc1) }
        { YLD(5, Yb0,Yb1,Yb2,Yb3) XLD(5, Xc0,Xc1) YMAT(Ya0,Ya1,Ya2,Ya3)
          FROW(0, Xb0,Xb1) FROW(1, Xa0,Xa1) }
        { YLD(6, Ya0,Ya1,Ya2,Ya3) XLD(6, Xa0,Xa1) YMAT(Yb0,Yb1,Yb2,Yb3)
          FROW(0, Xc0,Xc1) FROW(1, Xb0,Xb1) }
        { YLD(7, Yb0,Yb1,Yb2,Yb3) YMAT(Ya0,Ya1,Ya2,Ya3)
          FROW(0, Xa0,Xa1) FROW(1, Xc0,Xc1) }
        { YMAT(Yb0,Yb1,Yb2,Yb3)
          FROW(1, Xa0,Xa1) }
    }

    // ---- reduce over clane (lane bits 3,4,5) ----
#pragma unroll
    for (int m = 8; m <= 32; m <<= 1)
#pragma unroll
        for (int l = 0; l < 2; ++l)
#pragma unroll
            for (int b = 0; b < 8; ++b)
                acc[l][b] += __shfl_xor(acc[l][b], m, 64);

    __syncthreads();                 // all LDS reads done; overlay dists on v1s
    float* dlds = v1s;               // 8 q x 64 shifts = 512 floats
    if (clane == 0) {
#pragma unroll
        for (int l = 0; l < 2; ++l) {
            float* dp = &dlds[qwi*64 + (2*shq + l)*8];
            *(float4*)(dp)     = make_float4(acc[l][0], acc[l][1], acc[l][2], acc[l][3]);
            *(float4*)(dp + 4) = make_float4(acc[l][4], acc[l][5], acc[l][6], acc[l][7]);
        }
    }
    __syncthreads();

    // ---- top-7: 32 threads per query, 2 shift slots per lane ----
    {
        const int q8  = tid >> 5;        // 0..7
        const int l32 = tid & 31;
        const float* d = &dlds[q8 * 64];
        const int j0 = l32 * 2;
        float cv[2];
#pragma unroll
        for (int jj = 0; jj < 2; ++jj) {
            float v = d[j0 + jj];
            if (j0 + jj == 36) v += 1e30f;    // self bias (selection only)
            cv[jj] = v;
        }
        unsigned mask = 0;
        const int qxx = q0 + q8;
        const int q   = (t*NQ + qy)*NQ + qxx;
        float* od = out + q*KK;
        float* oi = out + (size_t)TT*NQ*NQ*KK + (size_t)q*KK*3;
        for (int k = 0; k < KK; ++k) {
            float best = -3.4e38f; int bi = 1 << 30;
#pragma unroll
            for (int jj = 0; jj < 2; ++jj)
                if (!(mask & (1u << jj)) && cv[jj] > best) { best = cv[jj]; bi = j0 + jj; }
#pragma unroll
            for (int m = 1; m <= 16; m <<= 1) {
                float ob = __shfl_xor(best, m, 64);
                int  obi = __shfl_xor(bi,  m, 64);
                if (ob > best || (ob == best && obi < bi)) { best = ob; bi = obi; }
            }
            if ((bi >> 1) == l32) mask |= 1u << (bi & 1);
            if (l32 == 0) {
                od[k] = d[bi];                 // unbiased value
                int dh = (bi >> 3) - 4;
                int dw = (bi & 7) - 4;
                oi[k*3 + 0] = (float)t;
                oi[k*3 + 1] = (float)refl(qh + dh, HH);
                oi[k*3 + 2] = (float)refl(qxx*4 + dw, WW);
            }
        }
    }
}

extern "C" void kernel_launch(void* const* d_in, const int* in_sizes, int n_in,
                              void* d_out, int out_size, void* d_ws, size_t ws_size,
                              hipStream_t stream) {
    (void)in_sizes; (void)n_in; (void)d_ws; (void)ws_size; (void)out_size;
    const float* vid0 = (const float*)d_in[0];
    const float* vid1 = (const float*)d_in[1];
    float* out = (float*)d_out;
    nls_kernel<<<dim3(TT * NQ * (NQ / QPB)), dim3(256), 0, stream>>>(vid0, vid1, out);
}